// Round 5
// baseline (38.830 us; speedup 1.0000x reference)
//
#include <hip/hip_runtime.h>

// RelationalAttentionContextEncoder2 — wave-per-batch, packed-f16, pre-scaled 1/15.
// v(i,j,h)/15 = a'(i,h) + c'(j,h) + w8'(h)*dist(i,j)   (coeffs pre-scaled by 1/15)
// rel[i,h] = sum_{j != i} relu(v')      (diagonal skipped at compile time)
// prop[i,h] = relu(wp0*ei2 + wp1*ei3 + bp)
//
// v6 vs v1-v5 (all 31.2-32.3 us; v5 readlane 35.0): TWO batches per wave,
// software-pipelined. Ledger says the bound is the write drain (134 MB,
// floor ~21 us) plus ~8-10 us that is either cohort-lockstep overlap loss
// or fixed launch overhead. This variant:
//  - grid = B/8; wave w of block beta does batches (beta*4+w) and (+nw).
//  - weights/coeffs loaded+derived ONCE per wave (was per batch).
//  - batch k+1's setup/compute overlaps batch k's store drain (stores are
//    fire-and-forget; no vmcnt waits anywhere).
//  - prop rows stored during the c2 pass -> write stream starts ~8KB earlier.
//  - LDS dist table (4KB/block) reused across reps; explicit lgkmcnt(0)
//    before rewrite guards the same-wave read-after-write hazard.

constexpr int NE = 16;
constexpr int HH = 128;

typedef _Float16 h2 __attribute__((ext_vector_type(2)));
typedef float vf2 __attribute__((ext_vector_type(2)));

struct f2 { float x, y; };
__device__ __forceinline__ f2 add2(f2 a, f2 b) { return {a.x + b.x, a.y + b.y}; }
__device__ __forceinline__ f2 sub2(f2 a, f2 b) { return {a.x - b.x, a.y - b.y}; }
__device__ __forceinline__ f2 fma2s(f2 w, float s, f2 c) {
    return {fmaf(w.x, s, c.x), fmaf(w.y, s, c.y)};
}
__device__ __forceinline__ f2 mul2s(f2 a, float s) { return {a.x * s, a.y * s}; }
__device__ __forceinline__ f2 relu2(f2 a) { return {fmaxf(a.x, 0.f), fmaxf(a.y, 0.f)}; }
__device__ __forceinline__ h2 mk_h2(float x, float y) {
    h2 r; r.x = (_Float16)x; r.y = (_Float16)y; return r;
}

__global__ __launch_bounds__(256, 8) void relctx_kernel(
    const float* __restrict__ ctx,     // [B, 64]
    const float* __restrict__ W_rel,   // [9, 128]
    const float* __restrict__ b_rel,   // [128]
    const float* __restrict__ W_prop,  // [2, 128]
    const float* __restrict__ b_prop,  // [128]
    float* __restrict__ out,           // [B, 16, 256]
    int B)
{
    // per-wave dist table: f16 splat per (i,j), packed 4 j's per uint4
    __shared__ uint4 s_d2[4][NE][NE / 4];

    const int tid = threadIdx.x;
    const int wave = __builtin_amdgcn_readfirstlane(tid >> 6);
    const int lane = tid & 63;
    const int nw = gridDim.x * 4;   // total waves = ceil(B/2)

    // ---- weights (h-pair per lane), pre-scaled by 1/15 — ONCE per wave
    constexpr float S = 1.0f / 15.0f;
    const f2* W2 = (const f2*)W_rel;   // [9][64]
    h2 w8h;
    f2 u2s, u3s, t0s, t1s, w4s, w5s, brs;
    {
        const f2 w0 = W2[0 * 64 + lane];
        const f2 w1 = W2[1 * 64 + lane];
        const f2 w2 = W2[2 * 64 + lane];
        const f2 w3 = W2[3 * 64 + lane];
        const f2 w4 = W2[4 * 64 + lane];
        const f2 w5 = W2[5 * 64 + lane];
        const f2 w6 = W2[6 * 64 + lane];
        const f2 w7 = W2[7 * 64 + lane];
        const f2 w8 = W2[8 * 64 + lane];
        const f2 br = ((const f2*)b_rel)[lane];
        u2s = mul2s(sub2(w2, w6), S);   // c' coeff of ej2
        u3s = mul2s(sub2(w3, w7), S);   // c' coeff of ej3
        t0s = mul2s(add2(w0, w6), S);   // a' coeff of ei2
        t1s = mul2s(add2(w1, w7), S);   // a' coeff of ei3
        w4s = mul2s(w4, S);
        w5s = mul2s(w5, S);
        brs = mul2s(br, S);
        w8h = mk_h2(w8.x * S, w8.y * S);
    }
    const f2 wp0 = ((const f2*)W_prop)[lane];
    const f2 wp1 = ((const f2*)W_prop)[64 + lane];
    const f2 bp  = ((const f2*)b_prop)[lane];
    const h2 hz = mk_h2(0.0f, 0.0f);

    #pragma unroll
    for (int rep = 0; rep < 2; ++rep) {
        const int b = blockIdx.x * 4 + wave + rep * nw;
        if (b >= B) break;   // no barriers anywhere -> early exit is safe

        const float* __restrict__ cb = ctx + (size_t)b * (NE * 4);
        const float4* __restrict__ cb4 = (const float4*)cb;
        float* __restrict__ ob = out + (size_t)b * NE * (2 * HH) + 2 * lane;

        // ---- Phase 1: dist table. lane -> i = lane>>2, j-quad = lane&3
        if (rep) {
            // same-wave RAW hazard: ensure batch-0's ds_reads retired
            asm volatile("s_waitcnt lgkmcnt(0)" ::: "memory");
        }
        {
            const int i = lane >> 2;
            const int jq = lane & 3;
            const float2 ei = *(const float2*)(cb + i * 4);
            unsigned q[4];
            #pragma unroll
            for (int t = 0; t < 4; ++t) {
                const int j = jq * 4 + t;
                const float2 ej = *(const float2*)(cb + j * 4);
                const float dx = ei.x - ej.x;
                const float dy = ei.y - ej.y;
                const float dist = sqrtf(fmaf(dx, dx, dy * dy));  // diag unused
                q[t] = __builtin_bit_cast(unsigned, mk_h2(dist, dist));
            }
            s_d2[wave][i][jq] = make_uint4(q[0], q[1], q[2], q[3]);
        }
        // table is wave-private: same-wave LDS ordering only, no block barrier
        asm volatile("s_waitcnt lgkmcnt(0)" ::: "memory");

        // ---- Pass A: c2[e] + prop store (write stream starts here)
        h2 c2[NE];
        #pragma unroll
        for (int e = 0; e < NE; ++e) {
            const float4 ev = cb4[e];
            f2 t = fma2s(u3s, ev.w, mul2s(u2s, ev.z));
            t = fma2s(w4s, -ev.x, t);
            t = fma2s(w5s, -ev.y, t);
            c2[e] = mk_h2(t.x, t.y);
            const f2 prop = relu2(fma2s(wp0, ev.z, fma2s(wp1, ev.w, bp)));
            vf2 pv; pv.x = prop.x; pv.y = prop.y;
            *(vf2*)(ob + (size_t)e * (2 * HH)) = pv;
        }

        // ---- Phase 3: all 16 i rows — pure pk-f16 hot loop
        #pragma unroll
        for (int i = 0; i < NE; ++i) {
            const float4 ev = cb4[i];
            f2 ai = fma2s(t0s, ev.z, brs);
            ai = fma2s(t1s, ev.w, ai);
            ai = fma2s(w4s, ev.x, ai);
            ai = fma2s(w5s, ev.y, ai);
            const h2 a = mk_h2(ai.x, ai.y);

            h2 a0 = hz, a1 = hz, a2 = hz, a3 = hz;
            #pragma unroll
            for (int jq = 0; jq < 4; ++jq) {
                const uint4 q = s_d2[wave][i][jq];   // uniform addr broadcast
                const unsigned qa[4] = {q.x, q.y, q.z, q.w};
                #pragma unroll
                for (int t = 0; t < 4; ++t) {
                    const int j = jq * 4 + t;
                    if (j == i) continue;            // compile-time diag skip
                    const h2 d2 = __builtin_bit_cast(h2, qa[t]);
                    h2 v = w8h * d2 + (a + c2[j]);        // pk_add + pk_fma
                    v = __builtin_elementwise_max(v, hz); // v_pk_max_f16
                    if (t == 0) a0 += v;
                    else if (t == 1) a1 += v;
                    else if (t == 2) a2 += v;
                    else a3 += v;
                }
            }
            const h2 s = (a0 + a1) + (a2 + a3);     // already /15-scaled
            vf2 rv; rv.x = (float)s.x; rv.y = (float)s.y;
            *(vf2*)(ob + (size_t)i * (2 * HH) + HH) = rv;
        }
    }
}

extern "C" void kernel_launch(void* const* d_in, const int* in_sizes, int n_in,
                              void* d_out, int out_size, void* d_ws, size_t ws_size,
                              hipStream_t stream) {
    const float* ctx    = (const float*)d_in[0];
    const float* W_rel  = (const float*)d_in[1];
    const float* b_rel  = (const float*)d_in[2];
    const float* W_prop = (const float*)d_in[3];
    const float* b_prop = (const float*)d_in[4];
    float* out = (float*)d_out;

    const int B = in_sizes[0] / (NE * 4);
    const int grid = (B + 7) / 8;   // 2 batches per wave
    relctx_kernel<<<grid, 256, 0, stream>>>(ctx, W_rel, b_rel, W_prop, b_prop, out, B);
}

// Round 6
// 30.930 us; speedup vs baseline: 1.2554x; 1.2554x over previous
//
#include <hip/hip_runtime.h>

// RelationalAttentionContextEncoder2 — wave-per-batch, packed-f16, pre-scaled 1/15.
// v(i,j,h)/15 = a'(i,h) + c'(j,h) + w8'(h)*dist(i,j)   (all coeffs pre-scaled by 1/15)
// rel[i,h] = sum_{j != i} relu(v')      (diagonal skipped at compile time)
// prop[i,h] = relu(wp0*ei2 + wp1*ei3 + bp)   (unscaled, f32)
// Each wave owns one batch (dist table wave-private -> no __syncthreads, only
// a same-wave lgkmcnt wait). Inner loop: 4 v_pk_*_f16 per (j, 2h).
//
// v7 == v1 (best measured: 30.8/31.2 us). Restored after the v5 (readlane,
// 35.0) and v6 (2-batch pipeline, 38.8: grid halved -> occupancy 43%)
// regressions. v6's rocprof showed WRITE_SIZE=147.8MB drains to HBM in-kernel
// and VALUBusy=19%: the kernel is write-drain-bound at ~4.8 TB/s effective
// (8192 concurrent 16KB streams vs fill's one sequential region at 6.5).
// v1-v4 (nt/plain stores, VGPR diet, store scheduling) all 31.2-32.3 us.

constexpr int NE = 16;
constexpr int HH = 128;

typedef _Float16 h2 __attribute__((ext_vector_type(2)));
typedef float vf2 __attribute__((ext_vector_type(2)));   // native vec for nt-store

struct f2 { float x, y; };
__device__ __forceinline__ f2 add2(f2 a, f2 b) { return {a.x + b.x, a.y + b.y}; }
__device__ __forceinline__ f2 sub2(f2 a, f2 b) { return {a.x - b.x, a.y - b.y}; }
__device__ __forceinline__ f2 fma2s(f2 w, float s, f2 c) {
    return {fmaf(w.x, s, c.x), fmaf(w.y, s, c.y)};
}
__device__ __forceinline__ f2 mul2s(f2 a, float s) { return {a.x * s, a.y * s}; }
__device__ __forceinline__ f2 relu2(f2 a) { return {fmaxf(a.x, 0.f), fmaxf(a.y, 0.f)}; }
__device__ __forceinline__ h2 mk_h2(float x, float y) {
    h2 r; r.x = (_Float16)x; r.y = (_Float16)y; return r;
}

__global__ __launch_bounds__(256) void relctx_kernel(
    const float* __restrict__ ctx,     // [B, 64]
    const float* __restrict__ W_rel,   // [9, 128]
    const float* __restrict__ b_rel,   // [128]
    const float* __restrict__ W_prop,  // [2, 128]
    const float* __restrict__ b_prop,  // [128]
    float* __restrict__ out,           // [B, 16, 256]
    int B)
{
    // per-wave dist table: f16 splat per (i,j), packed 4 j's per uint4
    __shared__ uint4 s_d2[4][NE][NE / 4];

    const int tid = threadIdx.x;
    const int wave = __builtin_amdgcn_readfirstlane(tid >> 6);  // scalar wave id
    const int lane = tid & 63;
    const int b = blockIdx.x * 4 + wave;
    if (b >= B) return;

    const float* __restrict__ cb = ctx + (size_t)b * (NE * 4);  // uniform base

    // ---- Phase 1: dist table. lane -> i = lane>>2, j-quad = lane&3 (covers all 16x4)
    {
        const int i = lane >> 2;
        const int jq = lane & 3;
        const float eix = cb[i * 4 + 0];
        const float eiy = cb[i * 4 + 1];
        unsigned q[4];
        #pragma unroll
        for (int t = 0; t < 4; ++t) {
            const int j = jq * 4 + t;
            const float dx = eix - cb[j * 4 + 0];
            const float dy = eiy - cb[j * 4 + 1];
            const float dist = sqrtf(fmaf(dx, dx, dy * dy));  // diag value unused
            q[t] = __builtin_bit_cast(unsigned, mk_h2(dist, dist));
        }
        s_d2[wave][i][jq] = make_uint4(q[0], q[1], q[2], q[3]);
    }
    // table is wave-private: same-wave LDS ordering only, no block barrier
    asm volatile("s_waitcnt lgkmcnt(0)" ::: "memory");

    // ---- Phase 2: weights (h-pair per lane), pre-scaled by 1/15
    const f2* W2 = (const f2*)W_rel;   // [9][64]
    const f2 w0 = W2[0 * 64 + lane];
    const f2 w1 = W2[1 * 64 + lane];
    const f2 w2 = W2[2 * 64 + lane];
    const f2 w3 = W2[3 * 64 + lane];
    const f2 w4 = W2[4 * 64 + lane];
    const f2 w5 = W2[5 * 64 + lane];
    const f2 w6 = W2[6 * 64 + lane];
    const f2 w7 = W2[7 * 64 + lane];
    const f2 w8 = W2[8 * 64 + lane];
    const f2 br  = ((const f2*)b_rel)[lane];
    const f2 wp0 = ((const f2*)W_prop)[lane];
    const f2 wp1 = ((const f2*)W_prop)[64 + lane];
    const f2 bp  = ((const f2*)b_prop)[lane];

    constexpr float S = 1.0f / 15.0f;
    const f2 u2s = mul2s(sub2(w2, w6), S);   // c' coeff of ej2
    const f2 u3s = mul2s(sub2(w3, w7), S);   // c' coeff of ej3
    const f2 t0s = mul2s(add2(w0, w6), S);   // a' coeff of ei2
    const f2 t1s = mul2s(add2(w1, w7), S);   // a' coeff of ei3
    const f2 w4s = mul2s(w4, S);
    const f2 w5s = mul2s(w5, S);
    const f2 brs = mul2s(br, S);
    const h2 w8h = mk_h2(w8.x * S, w8.y * S);
    const h2 hz = mk_h2(0.0f, 0.0f);

    // c'(j) in f32 from uniform (scalar-pipe) ents, rounded once to f16 pair
    h2 c2[NE];
    #pragma unroll
    for (int j = 0; j < NE; ++j) {
        f2 t = fma2s(u3s, cb[j * 4 + 3], mul2s(u2s, cb[j * 4 + 2]));
        t = fma2s(w4s, -cb[j * 4 + 0], t);
        t = fma2s(w5s, -cb[j * 4 + 1], t);
        c2[j] = mk_h2(t.x, t.y);
    }

    // ---- Phase 3: all 16 i rows
    #pragma unroll
    for (int i = 0; i < NE; ++i) {
        const float ei0 = cb[i * 4 + 0];
        const float ei1 = cb[i * 4 + 1];
        const float ei2 = cb[i * 4 + 2];
        const float ei3 = cb[i * 4 + 3];

        f2 ai = fma2s(t0s, ei2, brs);
        ai = fma2s(t1s, ei3, ai);
        ai = fma2s(w4s, ei0, ai);
        ai = fma2s(w5s, ei1, ai);
        const h2 ai2 = mk_h2(ai.x, ai.y);

        h2 a0 = hz, a1 = hz, a2 = hz, a3 = hz;
        #pragma unroll
        for (int jq = 0; jq < 4; ++jq) {
            const uint4 q = s_d2[wave][i][jq];   // uniform addr -> broadcast b128
            const unsigned qa[4] = {q.x, q.y, q.z, q.w};
            #pragma unroll
            for (int t = 0; t < 4; ++t) {
                const int j = jq * 4 + t;
                if (j == i) continue;            // compile-time diagonal skip
                const h2 d2 = __builtin_bit_cast(h2, qa[t]);
                h2 v = w8h * d2 + (ai2 + c2[j]);      // v_pk_fma / v_pk_add
                v = __builtin_elementwise_max(v, hz); // v_pk_max_f16
                if (t == 0) a0 += v;
                else if (t == 1) a1 += v;
                else if (t == 2) a2 += v;
                else a3 += v;
            }
        }
        const h2 s = (a0 + a1) + (a2 + a3);     // 2 pk adds; already /15-scaled
        const f2 prop = relu2(fma2s(wp0, ei2, fma2s(wp1, ei3, bp)));

        float* o = out + ((size_t)b * NE + i) * (2 * HH) + 2 * lane;
        vf2 pv; pv.x = prop.x; pv.y = prop.y;
        vf2 rv; rv.x = (float)s.x; rv.y = (float)s.y;
        __builtin_nontemporal_store(pv, (vf2*)o);
        __builtin_nontemporal_store(rv, (vf2*)(o + HH));
    }
}

extern "C" void kernel_launch(void* const* d_in, const int* in_sizes, int n_in,
                              void* d_out, int out_size, void* d_ws, size_t ws_size,
                              hipStream_t stream) {
    const float* ctx    = (const float*)d_in[0];
    const float* W_rel  = (const float*)d_in[1];
    const float* b_rel  = (const float*)d_in[2];
    const float* W_prop = (const float*)d_in[3];
    const float* b_prop = (const float*)d_in[4];
    float* out = (float*)d_out;

    const int B = in_sizes[0] / (NE * 4);
    const int grid = (B + 3) / 4;
    relctx_kernel<<<grid, 256, 0, stream>>>(ctx, W_rel, b_rel, W_prop, b_prop, out, B);
}